// Round 15
// baseline (166.869 us; speedup 1.0000x reference)
//
#include <hip/hip_runtime.h>
#include <hip/hip_bf16.h>

#define SS 2048
#define DD 512
#define HWIN 128

typedef __bf16 bf16x8 __attribute__((ext_vector_type(8)));
typedef unsigned short u16x8 __attribute__((ext_vector_type(8)));
typedef float f32x4 __attribute__((ext_vector_type(4)));

#define VMCNT0() asm volatile("s_waitcnt vmcnt(0)" ::: "memory")

__device__ __forceinline__ unsigned short f2bf(float x) {
    unsigned u = __builtin_bit_cast(unsigned, x);
    return (unsigned short)((u + 0x7fffu + ((u >> 16) & 1u)) >> 16);
}
__device__ __forceinline__ float bf2f(unsigned short s) {
    unsigned u = ((unsigned)s) << 16;
    return __builtin_bit_cast(float, u);
}
__device__ __forceinline__ void split_bf(float x, unsigned short& h, unsigned short& l) {
    h = f2bf(x);
    l = f2bf(x - bf2f(h));
}
__device__ __forceinline__ f32x4 mfma16(u16x8 a, u16x8 b, f32x4 c) {
    return __builtin_amdgcn_mfma_f32_16x16x32_bf16(
        __builtin_bit_cast(bf16x8, a), __builtin_bit_cast(bf16x8, b), c, 0, 0, 0);
}
// Direct global -> LDS DMA, 16 B per lane (dest = wave-uniform base + lane*16).
__device__ __forceinline__ void gload16(const unsigned short* g, unsigned short* l) {
    __builtin_amdgcn_global_load_lds(
        (const __attribute__((address_space(1))) unsigned int*)g,
        (__attribute__((address_space(3))) unsigned int*)l, 16, 0, 0);
}

// ---------------------------------------------------------------------------
// Cast everything once (unchanged).  q,k,v and Wq,Wk,Wv PLAIN-HI bf16;
// Wo paired hi/lo.
// ---------------------------------------------------------------------------
__global__ __launch_bounds__(256) void castAll(
    const float* __restrict__ q, const float* __restrict__ k, const float* __restrict__ v,
    const float* __restrict__ wq, const float* __restrict__ wk,
    const float* __restrict__ wv, const float* __restrict__ wo,
    unsigned short* __restrict__ QAh, unsigned short* __restrict__ KAh,
    unsigned short* __restrict__ VAh,
    unsigned short* __restrict__ WQh, unsigned short* __restrict__ WKh,
    unsigned short* __restrict__ WVh, unsigned short* __restrict__ WoP)
{
    const size_t e0 = ((size_t)blockIdx.x * 256 + threadIdx.x) * 8;
    const float* src; size_t off; unsigned short* dsth; bool paired = false;
    if      (e0 < 2097152) { src = q; off = e0;           dsth = QAh + off; }
    else if (e0 < 4194304) { src = k; off = e0 - 2097152; dsth = KAh + off; }
    else if (e0 < 6291456) { src = v; off = e0 - 4194304; dsth = VAh + off; }
    else {
        const size_t e = e0 - 6291456;
        if      (e < 262144) { src = wq; off = e;          dsth = WQh + off; }
        else if (e < 524288) { src = wk; off = e - 262144; dsth = WKh + off; }
        else if (e < 786432) { src = wv; off = e - 524288; dsth = WVh + off; }
        else { src = wo; off = e - 786432; dsth = WoP + 2 * (e - 786432); paired = true; }
    }
    const float4 f0 = *(const float4*)(src + off), f1 = *(const float4*)(src + off + 4);
    const float vals[8] = {f0.x, f0.y, f0.z, f0.w, f1.x, f1.y, f1.z, f1.w};
    u16x8 h;
    #pragma unroll
    for (int i = 0; i < 8; ++i) h[i] = f2bf(vals[i]);
    *(u16x8*)dsth = h;
    if (paired) {
        u16x8 l;
        #pragma unroll
        for (int i = 0; i < 8; ++i) l[i] = f2bf(vals[i] - bf2f(h[i]));
        *(u16x8*)(dsth + 8) = l;
    }
}

// ---------------------------------------------------------------------------
// proj GEMM (128x64 tile, BK=64, grid 768): C = A@W.T + bias.
// R15: BARRIER-FREE wave-private staging.  Each wave DMAs its OWN fragment
// copies (12 gload16/step) into a private 12 KiB LDS slab, waits
// s_waitcnt vmcnt(0) (same-wave DMA completion), computes.  No
// __syncthreads anywhere: waves slip freely, so the CU's implicit
// wave-overlap engine hides the staging latency (the block-wide barrier
// drain was the 7x-invariant floor of R0-R13).  Staged bytes and MFMA
// order per output unchanged => bit-identical.  LDS 48 KiB -> 3 blocks/CU.
// z<2: OH hi.  z==2: VTH hi + deterministic V column partials.
// ---------------------------------------------------------------------------
__global__ __launch_bounds__(256) void proj_gemm(
    const unsigned short* __restrict__ QAh, const unsigned short* __restrict__ KAh,
    const unsigned short* __restrict__ VAh,
    const unsigned short* __restrict__ WQh, const unsigned short* __restrict__ WKh,
    const unsigned short* __restrict__ WVh,
    const float* __restrict__ bq, const float* __restrict__ bk, const float* __restrict__ bv,
    unsigned short* __restrict__ base,
    unsigned short* __restrict__ VTH, float* __restrict__ part)
{
    const int d = blockIdx.x;              // 0..767
    const int hi = d >> 6, low = d & 63;
    const int x = low >> 3, rsw = low & 7;
    const int g = hi * 8 + rsw;            // 0..95
    const int y = g / 3, z = g - y * 3;    // y 0..31

    const unsigned short* Ap = (z == 0) ? QAh : ((z == 1) ? KAh : VAh);
    const unsigned short* Wp = (z == 0) ? WQh : ((z == 1) ? WKh : WVh);
    const float* bias = (z == 0) ? bq : ((z == 1) ? bk : bv);
    unsigned short* OH = base + (size_t)z * 4194304;

    const int m0 = y * 128, n0 = x * 64;

    // wave-private: [wave][khalf*4+i][lane*8] / [wave][khalf*2+j][lane*8]
    __shared__ unsigned short Aw[4][8][512];   // 32 KiB
    __shared__ unsigned short Bw[4][4][512];   // 16 KiB

    const int tid = threadIdx.x, wave = tid >> 6, lane = tid & 63;
    const int lm = lane & 15, lq = lane >> 4;
    const int wm = wave >> 1, wn = wave & 1;
    const int kb = lq * 8;

    f32x4 acc[4][2] = {};

    // per-wave global row bases (the frags this wave CONSUMES)
    size_t arow[4], brow[2];
    #pragma unroll
    for (int i = 0; i < 4; ++i)
        arow[i] = (size_t)(m0 + (wm * 4 + i) * 16 + lm) * 512;
    #pragma unroll
    for (int j = 0; j < 2; ++j)
        brow[j] = (size_t)(n0 + (wn * 2 + j) * 16 + lm) * 512;

    for (int k0 = 0; k0 < 512; k0 += 64) {
        #pragma unroll
        for (int s = 0; s < 2; ++s) {
            #pragma unroll
            for (int i = 0; i < 4; ++i)
                gload16(Ap + arow[i] + k0 + s * 32 + kb, &Aw[wave][s * 4 + i][lane * 8]);
            #pragma unroll
            for (int j = 0; j < 2; ++j)
                gload16(Wp + brow[j] + k0 + s * 32 + kb, &Bw[wave][s * 2 + j][lane * 8]);
        }
        VMCNT0();                         // own DMAs landed; no barrier

        #pragma unroll
        for (int s = 0; s < 2; ++s) {     // khalf 0 then 1 (order of two BK32 steps)
            u16x8 afh[4], bfh[2];
            #pragma unroll
            for (int i = 0; i < 4; ++i)
                afh[i] = *(const u16x8*)&Aw[wave][s * 4 + i][lane * 8];
            #pragma unroll
            for (int j = 0; j < 2; ++j)
                bfh[j] = *(const u16x8*)&Bw[wave][s * 2 + j][lane * 8];
            #pragma unroll
            for (int i = 0; i < 4; ++i)
                #pragma unroll
                for (int j = 0; j < 2; ++j)
                    acc[i][j] = mfma16(afh[i], bfh[j], acc[i][j]);
        }
    }

    if (z < 2) {
        #pragma unroll
        for (int i = 0; i < 4; ++i)
            #pragma unroll
            for (int j = 0; j < 2; ++j) {
                const int col = n0 + (wn * 2 + j) * 16 + lm;
                const float bv_ = bias[col];
                #pragma unroll
                for (int r = 0; r < 4; ++r) {
                    const int row = m0 + (wm * 4 + i) * 16 + lq * 4 + r;
                    OH[(size_t)row * 512 + col] = f2bf(acc[i][j][r] + bv_);
                }
            }
    } else {
        // epilogue: VTH hi write + deterministic column partials
        float csum[2] = {0.f, 0.f};
        #pragma unroll
        for (int i = 0; i < 4; ++i)
            #pragma unroll
            for (int j = 0; j < 2; ++j) {
                const int col = n0 + (wn * 2 + j) * 16 + lm;
                const float bv_ = bias[col];
                #pragma unroll
                for (int r = 0; r < 4; ++r) {
                    const int row = m0 + (wm * 4 + i) * 16 + lq * 4 + r;
                    const float vv = acc[i][j][r] + bv_;
                    csum[j] += vv;
                    const size_t vix =
                        (((size_t)(row >> 11) * 8 + (col >> 6)) * 64 + (col & 63)) * 2048
                        + (row & 2047);
                    VTH[vix] = f2bf(vv);
                }
            }
        // reduce over lq; wave half (wm) owns rowblock y*2+wm (64 rows)
        #pragma unroll
        for (int j = 0; j < 2; ++j) {
            float s = csum[j];
            s += __shfl_xor(s, 16);
            s += __shfl_xor(s, 32);
            if (lq == 0) {
                const int col = n0 + (wn * 2 + j) * 16 + lm;
                part[(size_t)(y * 2 + wm) * 512 + col] = s;
            }
        }
    }
}

// ---------------------------------------------------------------------------
// out GEMM, BK=64: 64x64 tile, grid 512.  R14 version (X hi-only, Wo split
// 2-product), unchanged this round to bound blast radius.
// ---------------------------------------------------------------------------
__global__ __launch_bounds__(256) void out_gemm(
    const unsigned short* __restrict__ XHg,
    const unsigned short* __restrict__ WoP, const float* __restrict__ bo,
    float* __restrict__ O)
{
    const int gid = blockIdx.x;            // 0..511
    const int rr = gid & 7, hi = gid >> 3;
    const int nblk = hi & 7, mhi = hi >> 3;
    const int mblk = mhi * 8 + rr;         // 0..63
    const int m0 = mblk * 64, n0 = nblk * 64;

    __shared__ unsigned short Ah[2 * 4096];
    __shared__ unsigned short Bh[2 * 4096], Bl[2 * 4096];

    const int tid = threadIdx.x, wave = tid >> 6, lane = tid & 63;
    const int lm = lane & 15, lq = lane >> 4;
    const int kb = lq * 8;

    f32x4 acc[4] = {};

    const int arow = m0 + wave * 16 + lm;
    const int brow = n0 + wave * 16 + lm;

    #define OSTAGE(k0_, bs)                                                     \
    {                                                                           \
        _Pragma("unroll")                                                       \
        for (int s = 0; s < 2; ++s) {                                           \
            const int o = (bs) * 4096 + ((s * 4 + wave) * 64 + lane) * 8;       \
            gload16(XHg + (size_t)arow * 512 + (k0_) + s * 32 + kb, &Ah[o]);    \
            const unsigned short* pw =                                          \
                WoP + 2 * ((size_t)brow * 512 + (k0_) + s * 32 + kb);           \
            gload16(pw,     &Bh[o]);                                            \
            gload16(pw + 8, &Bl[o]);                                            \
        }                                                                       \
    }

    OSTAGE(0, 0);
    __syncthreads();

    for (int t = 0; t < 8; ++t) {
        const int cur = t & 1;
        if (t < 7) OSTAGE((t + 1) * 64, cur ^ 1);

        #pragma unroll
        for (int s = 0; s < 2; ++s) {
            const u16x8 a_h = *(const u16x8*)&Ah[cur * 4096 + ((s * 4 + wave) * 64 + lane) * 8];
            #pragma unroll
            for (int j = 0; j < 4; ++j) {
                const u16x8 b_h = *(const u16x8*)&Bh[cur * 4096 + ((s * 4 + j) * 64 + lane) * 8];
                const u16x8 b_l = *(const u16x8*)&Bl[cur * 4096 + ((s * 4 + j) * 64 + lane) * 8];
                acc[j] = mfma16(a_h, b_h, acc[j]);
                acc[j] = mfma16(a_h, b_l, acc[j]);
            }
        }

        __syncthreads();
    }
    #undef OSTAGE

    #pragma unroll
    for (int j = 0; j < 4; ++j) {
        const int col = n0 + j * 16 + lm;
        const float bv_ = bo[col];
        #pragma unroll
        for (int r = 0; r < 4; ++r) {
            const int row = m0 + wave * 16 + lq * 4 + r;
            O[(size_t)row * 512 + col] = acc[j][r] + bv_;
        }
    }
}

// ---------------------------------------------------------------------------
// PLAIN-bf16 MFMA sliding-window attention.  R15: FULLY BARRIER-FREE.
// Each wave stages its OWN copies of the jt-tile's K and V fragments
// (16 gload16/thread/tile) into private LDS slabs, waits vmcnt(0), and
// computes; Swh was already wave-private (R5).  Zero __syncthreads.
// Staged bytes identical, MFMA order identical => bit-identical output.
// LDS 73 KiB -> 2 blocks/CU (= grid's 2/CU).
//   x = [ sum_win (e^s - 1) v + VS ] / ( 2048 + sum_win (e^s - 1) )
// ---------------------------------------------------------------------------
__global__ __launch_bounds__(256) void attn_mfma(
    const unsigned short* __restrict__ QH, const unsigned short* __restrict__ KH,
    const unsigned short* __restrict__ VTH, const float* __restrict__ part,
    unsigned short* __restrict__ XH)
{
    const int dblk = blockIdx.x;
    const int bhi = dblk >> 8, blow = dblk & 255;
    const int xblk = blow >> 3, rrs = blow & 7;
    const int bh = bhi * 8 + rrs;        // 0..15
    const int h = bh & 7, b = bh >> 3;
    const int i0 = xblk * 64;
    const int tid = threadIdx.x, wave = tid >> 6, lane = tid & 63;
    const int lm = lane & 15, lq = lane >> 4;
    const int kb = lq * 8;

    __shared__ unsigned short Kw[4][8][512];   // [wave][js*2+c][lane*8], 32 KiB
    __shared__ unsigned short Vw[4][8][512];   // [wave][d2*2+c][lane*8], 32 KiB
    __shared__ unsigned short Swh[64][72];     // [q][j], wave-private rows

    const size_t qoff = ((size_t)(b * SS + i0 + wave * 16 + lm)) * DD + h * 64 + kb;
    const u16x8 aQ0h = *(const u16x8*)(QH + qoff);
    const u16x8 aQ1h = *(const u16x8*)(QH + qoff + 32);

    f32x4 oacc[4] = {};
    float dacc[4] = {0.f, 0.f, 0.f, 0.f};

    for (int jt = 0; jt < 5; ++jt) {
        const int jt0 = i0 - 128 + jt * 64;

        // stage THIS wave's private copies of all K and V fragments
        #pragma unroll
        for (int js = 0; js < 4; ++js) {
            const int jrow = jt0 + js * 16 + lm;
            const int jrc = min(max(jrow, 0), SS - 1);
            const size_t kgb = ((size_t)(b * SS + jrc)) * DD + h * 64 + kb;
            gload16(KH + kgb,      &Kw[wave][js * 2 + 0][lane * 8]);
            gload16(KH + kgb + 32, &Kw[wave][js * 2 + 1][lane * 8]);
        }
        const int j0c = min(max(jt0 + kb, 0), SS - 8);
        const int j1c = min(max(jt0 + 32 + kb, 0), SS - 8);
        #pragma unroll
        for (int d2 = 0; d2 < 4; ++d2) {
            const size_t vr = ((size_t)(bh * 64 + d2 * 16 + lm)) * 2048;
            gload16(VTH + vr + j0c, &Vw[wave][d2 * 2 + 0][lane * 8]);
            gload16(VTH + vr + j1c, &Vw[wave][d2 * 2 + 1][lane * 8]);
        }
        VMCNT0();                         // own DMAs landed; no barrier

        const int rmin = i0 + wave * 16;  // this wave's q rows [rmin, rmin+15]

        #pragma unroll
        for (int js = 0; js < 4; ++js) {
            const int j0 = js * 16;
            const int cmin = jt0 + j0, cmax = cmin + 15;
            // wave-uniform full-mask test: whole 16x16 subtile out of window/bounds
            const bool skip = (cmax < 0) || (cmin >= SS) ||
                              (cmax < rmin - HWIN) || (cmin > rmin + 15 + HWIN);
            if (skip) {
                #pragma unroll
                for (int r = 0; r < 4; ++r)
                    Swh[wave * 16 + lq * 4 + r][j0 + lm] = 0;   // == f2bf(0.0f)
                continue;
            }
            const u16x8 bK0h = *(const u16x8*)&Kw[wave][js * 2 + 0][lane * 8];
            const u16x8 bK1h = *(const u16x8*)&Kw[wave][js * 2 + 1][lane * 8];
            f32x4 s = {0.f, 0.f, 0.f, 0.f};
            s = mfma16(aQ0h, bK0h, s);
            s = mfma16(aQ1h, bK1h, s);
            const int jg = jt0 + j0 + lm;
            const int iq = i0 + wave * 16 + lq * 4;
            #pragma unroll
            for (int r = 0; r < 4; ++r) {
                const int qi = iq + r;
                // unsigned-range trick: same truth table, 2 compares
                const bool in = ((unsigned)jg < (unsigned)SS) &&
                                ((unsigned)(jg - qi + HWIN) <= (unsigned)(2 * HWIN));
                const float w = in ? (__expf(s[r] * 0.125f) - 1.0f) : 0.0f;
                dacc[r] += w;
                Swh[wave * 16 + lq * 4 + r][j0 + lm] = f2bf(w);
            }
        }

        // Swh rows wave-private; within-wave LDS ordering suffices
        const u16x8 aP0h = *(const u16x8*)&Swh[wave * 16 + lm][kb];
        const u16x8 aP1h = *(const u16x8*)&Swh[wave * 16 + lm][kb + 32];
        #pragma unroll
        for (int s4 = 0; s4 < 4; ++s4) {
            const u16x8 bV0h = *(const u16x8*)&Vw[wave][s4 * 2 + 0][lane * 8];
            const u16x8 bV1h = *(const u16x8*)&Vw[wave][s4 * 2 + 1][lane * 8];
            oacc[s4] = mfma16(aP0h, bV0h, oacc[s4]);
            oacc[s4] = mfma16(aP1h, bV1h, oacc[s4]);
        }
    }

    #pragma unroll
    for (int r = 0; r < 4; ++r) {
        float v = dacc[r];
        v += __shfl_xor(v, 1);
        v += __shfl_xor(v, 2);
        v += __shfl_xor(v, 4);
        v += __shfl_xor(v, 8);
        dacc[r] = v + 2048.0f;
    }

    #pragma unroll
    for (int s4 = 0; s4 < 4; ++s4) {
        // VS = fixed-order sum of the 32 rowblock partials for this (b,col)
        const float* pp = part + (size_t)(b * 32) * 512 + h * 64 + s4 * 16 + lm;
        float vsv = 0.f;
        #pragma unroll 8
        for (int p = 0; p < 32; ++p) vsv += pp[(size_t)p * 512];
        #pragma unroll
        for (int r = 0; r < 4; ++r) {
            const int qrow = i0 + wave * 16 + lq * 4 + r;
            const float x = (oacc[s4][r] + vsv) / dacc[r];
            const size_t ix = ((size_t)(b * SS + qrow)) * DD + h * 64 + s4 * 16 + lm;
            XH[ix] = f2bf(x);
        }
    }
}

// ---------------------------------------------------------------------------
extern "C" void kernel_launch(void* const* d_in, const int* in_sizes, int n_in,
                              void* d_out, int out_size, void* d_ws, size_t ws_size,
                              hipStream_t stream)
{
    const float* query  = (const float*)d_in[0];
    const float* key_in = (const float*)d_in[1];
    const float* value  = (const float*)d_in[2];
    const float* Wq = (const float*)d_in[3]; const float* bq = (const float*)d_in[4];
    const float* Wk = (const float*)d_in[5]; const float* bk = (const float*)d_in[6];
    const float* Wv = (const float*)d_in[7]; const float* bv = (const float*)d_in[8];
    const float* Wo = (const float*)d_in[9]; const float* bo = (const float*)d_in[10];

    unsigned short* wsb = (unsigned short*)d_ws;
    unsigned short* QH  = wsb;                 // z=0 output (hi only)
    unsigned short* KH  = wsb + 4194304;       // z=1 output (hi only)
    unsigned short* VTH = wsb + 8388608;       // V transposed hi [bh][d][s]
    unsigned short* XH  = wsb + 12582912;
    unsigned short* WQh = wsb + 16777216;      // Wq hi plain (256K shorts)
    unsigned short* WKh = wsb + 17039360;      // Wk hi plain
    unsigned short* WVh = wsb + 17301504;      // Wv hi plain
    unsigned short* WoP = wsb + 17825792;      // Wo paired
    unsigned short* QAh = wsb + 18350080;      // q input hi plain (2M shorts)
    unsigned short* KAh = wsb + 20447232;      // k input hi plain
    unsigned short* VAh = wsb + 22544384;      // v input hi plain
    float* partp = (float*)((char*)d_ws + 63045632);   // 64x512 V partials

    castAll<<<3584, 256, 0, stream>>>(query, key_in, value, Wq, Wk, Wv, Wo,
                                      QAh, KAh, VAh, WQh, WKh, WVh, WoP);

    proj_gemm<<<768, 256, 0, stream>>>(QAh, KAh, VAh, WQh, WKh, WVh,
                                       bq, bk, bv, QH, VTH, partp);

    attn_mfma<<<512, 256, 0, stream>>>(QH, KH, VTH, partp, XH);

    out_gemm<<<512, 256, 0, stream>>>(XH, WoP, bo, (float*)d_out);
}

// Round 16
// 144.792 us; speedup vs baseline: 1.1525x; 1.1525x over previous
//
#include <hip/hip_runtime.h>
#include <hip/hip_bf16.h>

#define SS 2048
#define DD 512
#define HWIN 128

typedef __bf16 bf16x8 __attribute__((ext_vector_type(8)));
typedef unsigned short u16x8 __attribute__((ext_vector_type(8)));
typedef float f32x4 __attribute__((ext_vector_type(4)));

#define VMCNT0() asm volatile("s_waitcnt vmcnt(0)" ::: "memory")
#define VMCNT6() asm volatile("s_waitcnt vmcnt(6)" ::: "memory")
#define BARRIER() __builtin_amdgcn_s_barrier()

__device__ __forceinline__ unsigned short f2bf(float x) {
    unsigned u = __builtin_bit_cast(unsigned, x);
    return (unsigned short)((u + 0x7fffu + ((u >> 16) & 1u)) >> 16);
}
__device__ __forceinline__ float bf2f(unsigned short s) {
    unsigned u = ((unsigned)s) << 16;
    return __builtin_bit_cast(float, u);
}
__device__ __forceinline__ void split_bf(float x, unsigned short& h, unsigned short& l) {
    h = f2bf(x);
    l = f2bf(x - bf2f(h));
}
__device__ __forceinline__ f32x4 mfma16(u16x8 a, u16x8 b, f32x4 c) {
    return __builtin_amdgcn_mfma_f32_16x16x32_bf16(
        __builtin_bit_cast(bf16x8, a), __builtin_bit_cast(bf16x8, b), c, 0, 0, 0);
}
// Direct global -> LDS DMA, 16 B per lane (dest = wave-uniform base + lane*16).
__device__ __forceinline__ void gload16(const unsigned short* g, unsigned short* l) {
    __builtin_amdgcn_global_load_lds(
        (const __attribute__((address_space(1))) unsigned int*)g,
        (__attribute__((address_space(3))) unsigned int*)l, 16, 0, 0);
}

// ---------------------------------------------------------------------------
// Cast everything once (R14).  q,k,v and Wq,Wk,Wv PLAIN-HI bf16; Wo paired.
// ---------------------------------------------------------------------------
__global__ __launch_bounds__(256) void castAll(
    const float* __restrict__ q, const float* __restrict__ k, const float* __restrict__ v,
    const float* __restrict__ wq, const float* __restrict__ wk,
    const float* __restrict__ wv, const float* __restrict__ wo,
    unsigned short* __restrict__ QAh, unsigned short* __restrict__ KAh,
    unsigned short* __restrict__ VAh,
    unsigned short* __restrict__ WQh, unsigned short* __restrict__ WKh,
    unsigned short* __restrict__ WVh, unsigned short* __restrict__ WoP)
{
    const size_t e0 = ((size_t)blockIdx.x * 256 + threadIdx.x) * 8;
    const float* src; size_t off; unsigned short* dsth; bool paired = false;
    if      (e0 < 2097152) { src = q; off = e0;           dsth = QAh + off; }
    else if (e0 < 4194304) { src = k; off = e0 - 2097152; dsth = KAh + off; }
    else if (e0 < 6291456) { src = v; off = e0 - 4194304; dsth = VAh + off; }
    else {
        const size_t e = e0 - 6291456;
        if      (e < 262144) { src = wq; off = e;          dsth = WQh + off; }
        else if (e < 524288) { src = wk; off = e - 262144; dsth = WKh + off; }
        else if (e < 786432) { src = wv; off = e - 524288; dsth = WVh + off; }
        else { src = wo; off = e - 786432; dsth = WoP + 2 * (e - 786432); paired = true; }
    }
    const float4 f0 = *(const float4*)(src + off), f1 = *(const float4*)(src + off + 4);
    const float vals[8] = {f0.x, f0.y, f0.z, f0.w, f1.x, f1.y, f1.z, f1.w};
    u16x8 h;
    #pragma unroll
    for (int i = 0; i < 8; ++i) h[i] = f2bf(vals[i]);
    *(u16x8*)dsth = h;
    if (paired) {
        u16x8 l;
        #pragma unroll
        for (int i = 0; i < 8; ++i) l[i] = f2bf(vals[i] - bf2f(h[i]));
        *(u16x8*)(dsth + 8) = l;
    }
}

// ---------------------------------------------------------------------------
// proj GEMM (128x64 tile, BK=64, grid 768): C = A@W.T + bias.
// R16: COUNTED-VMCNT DOUBLE-BUFFER — the one untested scheduling cell.
// Per step: issue STAGE(t+1) into nxt buf; s_waitcnt vmcnt(6) (my STAGE(t)
// landed, t+1's 6 loads STAY IN FLIGHT); raw s_barrier (all waves' t-loads
// landed -> cur complete); compute(cur); raw s_barrier (all reads done ->
// cur overwritable next iter).  No vmcnt(0) drain in the loop — unlike R6's
// __syncthreads dbuf (drains) and R12-14 (drain adjacent to issue, full
// latency exposed 8x).  Staged bytes / MFMA order unchanged => bit-identical.
// LDS 48 KiB -> still 3 blocks/CU at grid 768.
// z<2: OH hi.  z==2: VTH hi + deterministic V column partials.
// ---------------------------------------------------------------------------
__global__ __launch_bounds__(256) void proj_gemm(
    const unsigned short* __restrict__ QAh, const unsigned short* __restrict__ KAh,
    const unsigned short* __restrict__ VAh,
    const unsigned short* __restrict__ WQh, const unsigned short* __restrict__ WKh,
    const unsigned short* __restrict__ WVh,
    const float* __restrict__ bq, const float* __restrict__ bk, const float* __restrict__ bv,
    unsigned short* __restrict__ base,
    unsigned short* __restrict__ VTH, float* __restrict__ part)
{
    const int d = blockIdx.x;              // 0..767
    const int hi = d >> 6, low = d & 63;
    const int x = low >> 3, rsw = low & 7;
    const int g = hi * 8 + rsw;            // 0..95
    const int y = g / 3, z = g - y * 3;    // y 0..31

    const unsigned short* Ap = (z == 0) ? QAh : ((z == 1) ? KAh : VAh);
    const unsigned short* Wp = (z == 0) ? WQh : ((z == 1) ? WKh : WVh);
    const float* bias = (z == 0) ? bq : ((z == 1) ? bk : bv);
    unsigned short* OH = base + (size_t)z * 4194304;

    const int m0 = y * 128, n0 = x * 64;

    // double-buffered: A [buf][khalf*8+frag][lane*8] (2x16 KiB),
    //                  B [buf][khalf*4+frag][lane*8] (2x8 KiB)
    __shared__ unsigned short Ah[2 * 8192];   // 32 KiB
    __shared__ unsigned short Bh[2 * 4096];   // 16 KiB

    const int tid = threadIdx.x, wave = tid >> 6, lane = tid & 63;
    const int lm = lane & 15, lq = lane >> 4;
    const int wm = wave >> 1, wn = wave & 1;
    const int kb = lq * 8;

    f32x4 acc[4][2] = {};

    const int ar0 = m0 + (wave * 2 + 0) * 16 + lm;
    const int ar1 = m0 + (wave * 2 + 1) * 16 + lm;
    const int br  = n0 + wave * 16 + lm;

    const int aoff0 = ((wave * 2 + 0) * 64 + lane) * 8;
    const int aoff1 = ((wave * 2 + 1) * 64 + lane) * 8;
    const int boff  = (wave * 64 + lane) * 8;

    // stage K-step k0_ into buffer bs: 6 gload16/thread, zero VALU
    #define PSTAGE(k0_, bs)                                                     \
    {                                                                           \
        gload16(Ap + (size_t)ar0 * 512 + (k0_) + kb,      &Ah[(bs) * 8192 + aoff0]); \
        gload16(Ap + (size_t)ar1 * 512 + (k0_) + kb,      &Ah[(bs) * 8192 + aoff1]); \
        gload16(Wp + (size_t)br  * 512 + (k0_) + kb,      &Bh[(bs) * 4096 + boff]);  \
        gload16(Ap + (size_t)ar0 * 512 + (k0_) + 32 + kb, &Ah[(bs) * 8192 + 4096 + aoff0]); \
        gload16(Ap + (size_t)ar1 * 512 + (k0_) + 32 + kb, &Ah[(bs) * 8192 + 4096 + aoff1]); \
        gload16(Wp + (size_t)br  * 512 + (k0_) + 32 + kb, &Bh[(bs) * 4096 + 2048 + boff]);  \
    }

    PSTAGE(0, 0);
    VMCNT0();
    BARRIER();                             // prologue: buf0 complete everywhere

    for (int t = 0; t < 8; ++t) {
        const int cur = t & 1;
        if (t < 7) {
            PSTAGE((t + 1) * 64, cur ^ 1); // 6 loads fly across both barriers
            VMCNT6();                      // my STAGE(t) landed (6 newest stay)
        } else {
            VMCNT0();                      // last step: nothing new in flight
        }
        BARRIER();                         // all waves' STAGE(t) landed

        #pragma unroll
        for (int s = 0; s < 2; ++s) {      // khalf 0 then 1 (two BK32 steps' order)
            u16x8 afh[4], bfh[2];
            #pragma unroll
            for (int i = 0; i < 4; ++i)
                afh[i] = *(const u16x8*)&Ah[cur * 8192 + s * 4096 + ((wm * 4 + i) * 64 + lane) * 8];
            #pragma unroll
            for (int j = 0; j < 2; ++j)
                bfh[j] = *(const u16x8*)&Bh[cur * 4096 + s * 2048 + ((wn * 2 + j) * 64 + lane) * 8];
            #pragma unroll
            for (int i = 0; i < 4; ++i)
                #pragma unroll
                for (int j = 0; j < 2; ++j)
                    acc[i][j] = mfma16(afh[i], bfh[j], acc[i][j]);
        }

        BARRIER();                         // all reads of cur done -> overwritable
    }
    #undef PSTAGE

    if (z < 2) {
        #pragma unroll
        for (int i = 0; i < 4; ++i)
            #pragma unroll
            for (int j = 0; j < 2; ++j) {
                const int col = n0 + (wn * 2 + j) * 16 + lm;
                const float bv_ = bias[col];
                #pragma unroll
                for (int r = 0; r < 4; ++r) {
                    const int row = m0 + (wm * 4 + i) * 16 + lq * 4 + r;
                    OH[(size_t)row * 512 + col] = f2bf(acc[i][j][r] + bv_);
                }
            }
    } else {
        // epilogue: VTH hi write + deterministic column partials
        float csum[2] = {0.f, 0.f};
        #pragma unroll
        for (int i = 0; i < 4; ++i)
            #pragma unroll
            for (int j = 0; j < 2; ++j) {
                const int col = n0 + (wn * 2 + j) * 16 + lm;
                const float bv_ = bias[col];
                #pragma unroll
                for (int r = 0; r < 4; ++r) {
                    const int row = m0 + (wm * 4 + i) * 16 + lq * 4 + r;
                    const float vv = acc[i][j][r] + bv_;
                    csum[j] += vv;
                    const size_t vix =
                        (((size_t)(row >> 11) * 8 + (col >> 6)) * 64 + (col & 63)) * 2048
                        + (row & 2047);
                    VTH[vix] = f2bf(vv);
                }
            }
        // reduce over lq; wave half (wm) owns rowblock y*2+wm (64 rows)
        #pragma unroll
        for (int j = 0; j < 2; ++j) {
            float s = csum[j];
            s += __shfl_xor(s, 16);
            s += __shfl_xor(s, 32);
            if (lq == 0) {
                const int col = n0 + (wn * 2 + j) * 16 + lm;
                part[(size_t)(y * 2 + wm) * 512 + col] = s;
            }
        }
    }
}

// ---------------------------------------------------------------------------
// out GEMM, BK=64: 64x64 tile, grid 512.  R14 version (X hi-only, Wo split
// 2-product).  Unchanged.
// ---------------------------------------------------------------------------
__global__ __launch_bounds__(256) void out_gemm(
    const unsigned short* __restrict__ XHg,
    const unsigned short* __restrict__ WoP, const float* __restrict__ bo,
    float* __restrict__ O)
{
    const int gid = blockIdx.x;            // 0..511
    const int rr = gid & 7, hi = gid >> 3;
    const int nblk = hi & 7, mhi = hi >> 3;
    const int mblk = mhi * 8 + rr;         // 0..63
    const int m0 = mblk * 64, n0 = nblk * 64;

    __shared__ unsigned short Ah[2 * 4096];
    __shared__ unsigned short Bh[2 * 4096], Bl[2 * 4096];

    const int tid = threadIdx.x, wave = tid >> 6, lane = tid & 63;
    const int lm = lane & 15, lq = lane >> 4;
    const int kb = lq * 8;

    f32x4 acc[4] = {};

    const int arow = m0 + wave * 16 + lm;
    const int brow = n0 + wave * 16 + lm;

    #define OSTAGE(k0_, bs)                                                     \
    {                                                                           \
        _Pragma("unroll")                                                       \
        for (int s = 0; s < 2; ++s) {                                           \
            const int o = (bs) * 4096 + ((s * 4 + wave) * 64 + lane) * 8;       \
            gload16(XHg + (size_t)arow * 512 + (k0_) + s * 32 + kb, &Ah[o]);    \
            const unsigned short* pw =                                          \
                WoP + 2 * ((size_t)brow * 512 + (k0_) + s * 32 + kb);           \
            gload16(pw,     &Bh[o]);                                            \
            gload16(pw + 8, &Bl[o]);                                            \
        }                                                                       \
    }

    OSTAGE(0, 0);
    __syncthreads();

    for (int t = 0; t < 8; ++t) {
        const int cur = t & 1;
        if (t < 7) OSTAGE((t + 1) * 64, cur ^ 1);

        #pragma unroll
        for (int s = 0; s < 2; ++s) {
            const u16x8 a_h = *(const u16x8*)&Ah[cur * 4096 + ((s * 4 + wave) * 64 + lane) * 8];
            #pragma unroll
            for (int j = 0; j < 4; ++j) {
                const u16x8 b_h = *(const u16x8*)&Bh[cur * 4096 + ((s * 4 + j) * 64 + lane) * 8];
                const u16x8 b_l = *(const u16x8*)&Bl[cur * 4096 + ((s * 4 + j) * 64 + lane) * 8];
                acc[j] = mfma16(a_h, b_h, acc[j]);
                acc[j] = mfma16(a_h, b_l, acc[j]);
            }
        }

        __syncthreads();
    }
    #undef OSTAGE

    #pragma unroll
    for (int j = 0; j < 4; ++j) {
        const int col = n0 + j * 16 + lm;
        const float bv_ = bo[col];
        #pragma unroll
        for (int r = 0; r < 4; ++r) {
            const int row = m0 + wave * 16 + lq * 4 + r;
            O[(size_t)row * 512 + col] = acc[j][r] + bv_;
        }
    }
}

// ---------------------------------------------------------------------------
// PLAIN-bf16 MFMA sliding-window attention.  R14 version (barrier-diet dbuf,
// masked-subtile skip, deterministic VS-from-partials, X hi-only).
// Unchanged: its drain already sits after compute (loads fly under compute).
//   x = [ sum_win (e^s - 1) v + VS ] / ( 2048 + sum_win (e^s - 1) )
// ---------------------------------------------------------------------------
__global__ __launch_bounds__(256) void attn_mfma(
    const unsigned short* __restrict__ QH, const unsigned short* __restrict__ KH,
    const unsigned short* __restrict__ VTH, const float* __restrict__ part,
    unsigned short* __restrict__ XH)
{
    const int dblk = blockIdx.x;
    const int bhi = dblk >> 8, blow = dblk & 255;
    const int xblk = blow >> 3, rrs = blow & 7;
    const int bh = bhi * 8 + rrs;        // 0..15
    const int h = bh & 7, b = bh >> 3;
    const int i0 = xblk * 64;
    const int tid = threadIdx.x, wave = tid >> 6, lane = tid & 63;
    const int lm = lane & 15, lq = lane >> 4;
    const int kb = lq * 8;

    __shared__ unsigned short KfH[2 * 8 * 64 * 8];   // [buf][js*2+c][lane][8]
    __shared__ unsigned short VfH[2 * 8 * 64 * 8];   // [buf][s4*2+c][lane][8]
    __shared__ unsigned short Swh[64][72];           // [q][j], wave-private rows

    const size_t qoff = ((size_t)(b * SS + i0 + wave * 16 + lm)) * DD + h * 64 + kb;
    const u16x8 aQ0h = *(const u16x8*)(QH + qoff);
    const u16x8 aQ1h = *(const u16x8*)(QH + qoff + 32);

    f32x4 oacc[4] = {};
    float dacc[4] = {0.f, 0.f, 0.f, 0.f};

    const size_t vrow = ((size_t)bh * 64 + wave * 16 + lm) * 2048;
    const int s0 = (wave * 2 + 0) * 64 * 8 + lane * 8;   // this wave's slot bases
    const int s1 = (wave * 2 + 1) * 64 * 8 + lane * 8;

    // stage K/V tile jt_ into buffer bufsel
    #define STAGE(jt_, bufsel)                                                  \
    {                                                                           \
        const int jt0_ = i0 - 128 + (jt_) * 64;                                 \
        const int jrow = jt0_ + wave * 16 + lm;                                 \
        const int jrc = min(max(jrow, 0), SS - 1);                              \
        const size_t kgb = ((size_t)(b * SS + jrc)) * DD + h * 64 + kb;         \
        gload16(KH + kgb,      &KfH[(bufsel) * 4096 + s0]);                     \
        gload16(KH + kgb + 32, &KfH[(bufsel) * 4096 + s1]);                     \
        const int j0c = min(max(jt0_ + kb, 0), SS - 8);                         \
        const int j1c = min(max(jt0_ + 32 + kb, 0), SS - 8);                    \
        gload16(VTH + vrow + j0c, &VfH[(bufsel) * 4096 + s0]);                  \
        gload16(VTH + vrow + j1c, &VfH[(bufsel) * 4096 + s1]);                  \
    }

    STAGE(0, 0);
    __syncthreads();

    for (int jt = 0; jt < 5; ++jt) {
        const int buf = jt & 1;
        if (jt < 4) STAGE(jt + 1, buf ^ 1);   // in flight under this jt's compute
        const int jt0 = i0 - 128 + jt * 64;
        const int rmin = i0 + wave * 16;      // this wave's q rows [rmin, rmin+15]

        #pragma unroll
        for (int js = 0; js < 4; ++js) {
            const int j0 = js * 16;
            const int cmin = jt0 + j0, cmax = cmin + 15;
            // wave-uniform full-mask test: whole 16x16 subtile out of window/bounds
            const bool skip = (cmax < 0) || (cmin >= SS) ||
                              (cmax < rmin - HWIN) || (cmin > rmin + 15 + HWIN);
            if (skip) {
                #pragma unroll
                for (int r = 0; r < 4; ++r)
                    Swh[wave * 16 + lq * 4 + r][j0 + lm] = 0;   // == f2bf(0.0f)
                continue;
            }
            const u16x8 bK0h = *(const u16x8*)&KfH[buf * 4096 + ((js * 2 + 0) * 64 + lane) * 8];
            const u16x8 bK1h = *(const u16x8*)&KfH[buf * 4096 + ((js * 2 + 1) * 64 + lane) * 8];
            f32x4 s = {0.f, 0.f, 0.f, 0.f};
            s = mfma16(aQ0h, bK0h, s);
            s = mfma16(aQ1h, bK1h, s);
            const int jg = jt0 + j0 + lm;
            const int iq = i0 + wave * 16 + lq * 4;
            #pragma unroll
            for (int r = 0; r < 4; ++r) {
                const int qi = iq + r;
                // unsigned-range trick: same truth table, 2 compares
                const bool in = ((unsigned)jg < (unsigned)SS) &&
                                ((unsigned)(jg - qi + HWIN) <= (unsigned)(2 * HWIN));
                const float w = in ? (__expf(s[r] * 0.125f) - 1.0f) : 0.0f;
                dacc[r] += w;
                Swh[wave * 16 + lq * 4 + r][j0 + lm] = f2bf(w);
            }
        }

        // no barrier: Swh rows are wave-private (write/read by same wave)
        const u16x8 aP0h = *(const u16x8*)&Swh[wave * 16 + lm][kb];
        const u16x8 aP1h = *(const u16x8*)&Swh[wave * 16 + lm][kb + 32];
        #pragma unroll
        for (int s4 = 0; s4 < 4; ++s4) {
            const u16x8 bV0h = *(const u16x8*)&VfH[buf * 4096 + ((s4 * 2 + 0) * 64 + lane) * 8];
            const u16x8 bV1h = *(const u16x8*)&VfH[buf * 4096 + ((s4 * 2 + 1) * 64 + lane) * 8];
            oacc[s4] = mfma16(aP0h, bV0h, oacc[s4]);
            oacc[s4] = mfma16(aP1h, bV1h, oacc[s4]);
        }
        __syncthreads();   // next buf staged + this buf's reads done
    }
    #undef STAGE

    #pragma unroll
    for (int r = 0; r < 4; ++r) {
        float v = dacc[r];
        v += __shfl_xor(v, 1);
        v += __shfl_xor(v, 2);
        v += __shfl_xor(v, 4);
        v += __shfl_xor(v, 8);
        dacc[r] = v + 2048.0f;
    }

    #pragma unroll
    for (int s4 = 0; s4 < 4; ++s4) {
        // VS = fixed-order sum of the 32 rowblock partials for this (b,col)
        const float* pp = part + (size_t)(b * 32) * 512 + h * 64 + s4 * 16 + lm;
        float vsv = 0.f;
        #pragma unroll 8
        for (int p = 0; p < 32; ++p) vsv += pp[(size_t)p * 512];
        #pragma unroll
        for (int r = 0; r < 4; ++r) {
            const int qrow = i0 + wave * 16 + lq * 4 + r;
            const float x = (oacc[s4][r] + vsv) / dacc[r];
            const size_t ix = ((size_t)(b * SS + qrow)) * DD + h * 64 + s4 * 16 + lm;
            XH[ix] = f2bf(x);
        }
    }
}

// ---------------------------------------------------------------------------
extern "C" void kernel_launch(void* const* d_in, const int* in_sizes, int n_in,
                              void* d_out, int out_size, void* d_ws, size_t ws_size,
                              hipStream_t stream)
{
    const float* query  = (const float*)d_in[0];
    const float* key_in = (const float*)d_in[1];
    const float* value  = (const float*)d_in[2];
    const float* Wq = (const float*)d_in[3]; const float* bq = (const float*)d_in[4];
    const float* Wk = (const float*)d_in[5]; const float* bk = (const float*)d_in[6];
    const float* Wv = (const float*)d_in[7]; const float* bv = (const float*)d_in[8];
    const float* Wo = (const float*)d_in[9]; const float* bo = (const float*)d_in[10];

    unsigned short* wsb = (unsigned short*)d_ws;
    unsigned short* QH  = wsb;                 // z=0 output (hi only)
    unsigned short* KH  = wsb + 4194304;       // z=1 output (hi only)
    unsigned short* VTH = wsb + 8388608;       // V transposed hi [bh][d][s]
    unsigned short* XH  = wsb + 12582912;
    unsigned short* WQh = wsb + 16777216;      // Wq hi plain (256K shorts)
    unsigned short* WKh = wsb + 17039360;      // Wk hi plain
    unsigned short* WVh = wsb + 17301504;      // Wv hi plain
    unsigned short* WoP = wsb + 17825792;      // Wo paired
    unsigned short* QAh = wsb + 18350080;      // q input hi plain (2M shorts)
    unsigned short* KAh = wsb + 20447232;      // k input hi plain
    unsigned short* VAh = wsb + 22544384;      // v input hi plain
    float* partp = (float*)((char*)d_ws + 63045632);   // 64x512 V partials

    castAll<<<3584, 256, 0, stream>>>(query, key_in, value, Wq, Wk, Wv, Wo,
                                      QAh, KAh, VAh, WQh, WKh, WVh, WoP);

    proj_gemm<<<768, 256, 0, stream>>>(QAh, KAh, VAh, WQh, WKh, WVh,
                                       bq, bk, bv, QH, VTH, partp);

    attn_mfma<<<512, 256, 0, stream>>>(QH, KH, VTH, partp, XH);

    out_gemm<<<512, 256, 0, stream>>>(XH, WoP, bo, (float*)d_out);
}